// Round 1
// baseline (554.087 us; speedup 1.0000x reference)
//
#include <hip/hip_runtime.h>

#define NEG_SLOPE 0.2f

// ---------------- scores: su[n,o] = x[n,:]·w_u[o,:] + b_u[o], sv likewise (no bias)
__global__ __launch_bounds__(256) void scores_kernel(
    const float* __restrict__ x, const float* __restrict__ wu,
    const float* __restrict__ bu, const float* __restrict__ wv,
    float* __restrict__ su, float* __restrict__ sv, int N)
{
    __shared__ float wlds[32 * 129];   // pad 129: bank (o+k)%32 -> conflict-free
    int tid = threadIdx.x;
    for (int i = tid; i < 4096; i += 256) {
        int o = i >> 7, k = i & 127;
        wlds[o * 129 + k] = (o < 16) ? wu[i] : wv[i - 2048];
    }
    __syncthreads();
    int o = tid & 31;
    int n = blockIdx.x * 8 + (tid >> 5);
    if (n >= N) return;
    const float* xr = x + (size_t)n * 128;
    float acc = 0.f;
#pragma unroll
    for (int k = 0; k < 128; k += 4) {
        acc = fmaf(xr[k],     wlds[o * 129 + k],     acc);
        acc = fmaf(xr[k + 1], wlds[o * 129 + k + 1], acc);
        acc = fmaf(xr[k + 2], wlds[o * 129 + k + 2], acc);
        acc = fmaf(xr[k + 3], wlds[o * 129 + k + 3], acc);
    }
    if (o < 16) su[n * 16 + o] = acc + bu[o];
    else        sv[n * 16 + (o - 16)] = acc;
}

// ---------------- out[:, 0:128] = x
__global__ __launch_bounds__(256) void copyx_kernel(
    const float4* __restrict__ x4, float4* __restrict__ out4, int total)
{
    int idx = blockIdx.x * 256 + threadIdx.x;
    if (idx >= total) return;
    int n = idx >> 5, q = idx & 31;           // 32 float4 per x-row, 96 per out-row
    out4[(size_t)n * 96 + q] = x4[idx];
}

// ---------------- CSR build: histogram of dst
__global__ __launch_bounds__(256) void hist_kernel(
    const int* __restrict__ d0, const int* __restrict__ d1,
    int* __restrict__ cnt, int N, int E)
{
    int idx = blockIdx.x * 256 + threadIdx.x;
    if (idx >= 2 * E) return;
    int t = (idx >= E) ? 1 : 0;
    int dst = t ? d1[idx - E] : d0[idx];
    atomicAdd(cnt + t * N + dst, 1);
}

// ---------------- exclusive scan (one block per edge-set)
__global__ __launch_bounds__(1024) void scan_kernel(
    const int* __restrict__ cnt, int* __restrict__ off, int* __restrict__ cursor, int N)
{
    int t = blockIdx.x;
    const int* c = cnt + t * N;
    int* o = off + t * (N + 1);
    int* cur = cursor + t * N;
    __shared__ int lds[1024];
    __shared__ int carry_s;
    int tid = threadIdx.x;
    if (tid == 0) carry_s = 0;
    __syncthreads();
    for (int base = 0; base < N; base += 1024) {
        int i = base + tid;
        int val = (i < N) ? c[i] : 0;
        lds[tid] = val;
        __syncthreads();
        for (int d = 1; d < 1024; d <<= 1) {
            int add = (tid >= d) ? lds[tid - d] : 0;
            __syncthreads();
            lds[tid] += add;
            __syncthreads();
        }
        int excl = lds[tid] - val;
        int carry = carry_s;
        if (i < N) { int v = carry + excl; o[i] = v; cur[i] = v; }
        __syncthreads();
        if (tid == 0) carry_s = carry + lds[1023];
        __syncthreads();
    }
    if (tid == 0) o[N] = carry_s;
}

// ---------------- scatter src into dst-buckets
__global__ __launch_bounds__(256) void fill_kernel(
    const int* __restrict__ s0, const int* __restrict__ d0,
    const int* __restrict__ s1, const int* __restrict__ d1,
    int* __restrict__ cursor, int* __restrict__ bucket, int N, int E)
{
    int idx = blockIdx.x * 256 + threadIdx.x;
    if (idx >= 2 * E) return;
    int t = (idx >= E) ? 1 : 0;
    int e = t ? idx - E : idx;
    int dst = t ? d1[e] : d0[e];
    int src = t ? s1[e] : s0[e];
    int pos = atomicAdd(cursor + t * N + dst, 1);
    bucket[(size_t)t * E + pos] = src;
}

// ---------------- per-destination softmax + aggregation: one wave per node
__global__ __launch_bounds__(256) void agg_kernel(
    const float* __restrict__ x, const float* __restrict__ su,
    const float* __restrict__ sv, const int* __restrict__ off,
    const int* __restrict__ bucket, float* __restrict__ out, int N, int E)
{
    int t = blockIdx.y;
    int lane = threadIdx.x & 63;
    int n = blockIdx.x * 4 + (threadIdx.x >> 6);
    if (n >= N) return;
    const int* offt = off + t * (N + 1);
    const int* bkt = bucket + (size_t)t * E;
    int beg = offt[n], end = offt[n + 1];
    int h = lane & 7;                               // this lane's head class
    float vh = sv[n * 16 + t * 8 + h];

    // ---- pass 1: online softmax (m,l) per head; 8 edge-stripes x 8 heads
    float m = -INFINITY, l = 0.f;
    for (int i = beg + (lane >> 3); i < end; i += 8) {
        int src = bkt[i];
        float s = su[src * 16 + t * 8 + h] + vh;
        s = (s >= 0.f) ? s : NEG_SLOPE * s;
        float nm = fmaxf(m, s);
        l = l * __expf(m - nm) + __expf(s - nm);
        m = nm;
    }
#pragma unroll
    for (int d = 8; d < 64; d <<= 1) {              // reduce stripes, keep head class
        float mo = __shfl_xor(m, d);
        float lo = __shfl_xor(l, d);
        float nm = fmaxf(m, mo);
        float nl = (nm == -INFINITY) ? 0.f
                 : (l * __expf(m - nm) + lo * __expf(mo - nm));
        m = nm; l = nl;
    }
    float invl = (l > 0.f) ? (1.f / l) : 0.f;

    // ---- pass 2: gather x[src] rows, weight by p[head(j)], accumulate
    int j0 = lane * 2;
    int ha = j0 & 7, hb = (j0 + 1) & 7;
    float acc0 = 0.f, acc1 = 0.f;
    for (int cbeg = beg; cbeg < end; cbeg += 64) {
        int cnt = min(cbeg + 64, end) - cbeg;
        int mysrc = (cbeg + lane < end) ? bkt[cbeg + lane] : 0;
        for (int i = 0; i < cnt; ++i) {
            int src = __shfl(mysrc, i);
            float s = su[src * 16 + t * 8 + h] + vh;
            s = (s >= 0.f) ? s : NEG_SLOPE * s;
            float p = __expf(s - m) * invl;          // valid for lanes 0..7 (per-head)
            float pa = __shfl(p, ha);
            float pb = __shfl(p, hb);
            float2 xv = *(const float2*)(x + (size_t)src * 128 + j0);
            acc0 = fmaf(xv.x, pa, acc0);
            acc1 = fmaf(xv.y, pb, acc1);
        }
    }
    float2* orow = (float2*)(out + (size_t)n * 384 + 128 + t * 128 + j0);
    *orow = make_float2(acc0, acc1);
}

extern "C" void kernel_launch(void* const* d_in, const int* in_sizes, int n_in,
                              void* d_out, int out_size, void* d_ws, size_t ws_size,
                              hipStream_t stream)
{
    const float* x  = (const float*)d_in[0];
    const float* wu = (const float*)d_in[1];
    const float* bu = (const float*)d_in[2];
    const float* wv = (const float*)d_in[3];
    const int* s0 = (const int*)d_in[4];
    const int* d0 = (const int*)d_in[5];
    const int* s1 = (const int*)d_in[6];
    const int* d1 = (const int*)d_in[7];
    float* out = (float*)d_out;
    int N = in_sizes[0] / 128;
    int E = in_sizes[4];

    char* ws = (char*)d_ws;
    size_t o = 0;
    auto alloc = [&](size_t bytes) -> void* {
        void* p = ws + o;
        o = (o + bytes + 255) & ~(size_t)255;
        return p;
    };
    float* su    = (float*)alloc((size_t)N * 16 * 4);
    float* sv    = (float*)alloc((size_t)N * 16 * 4);
    int* cnt     = (int*)alloc((size_t)2 * N * 4);
    int* cursor  = (int*)alloc((size_t)2 * N * 4);
    int* off     = (int*)alloc((size_t)2 * (N + 1) * 4);
    int* bucket  = (int*)alloc((size_t)2 * E * 4);

    hipMemsetAsync(cnt, 0, (size_t)2 * N * 4, stream);
    scores_kernel<<<(N + 7) / 8, 256, 0, stream>>>(x, wu, bu, wv, su, sv, N);
    copyx_kernel<<<((N * 32) + 255) / 256, 256, 0, stream>>>(
        (const float4*)x, (float4*)out, N * 32);
    hist_kernel<<<((2 * E) + 255) / 256, 256, 0, stream>>>(d0, d1, cnt, N, E);
    scan_kernel<<<2, 1024, 0, stream>>>(cnt, off, cursor, N);
    fill_kernel<<<((2 * E) + 255) / 256, 256, 0, stream>>>(
        s0, d0, s1, d1, cursor, bucket, N, E);
    agg_kernel<<<dim3((N + 3) / 4, 2), 256, 0, stream>>>(
        x, su, sv, off, bucket, out, N, E);
}

// Round 2
// 435.351 us; speedup vs baseline: 1.2727x; 1.2727x over previous
//
#include <hip/hip_runtime.h>

#define NEG_SLOPE 0.2f
#define CHUNK 2048

__device__ __forceinline__ ushort f2bf(float f) {
    union { float f; unsigned u; } c; c.f = f;
    unsigned u = c.u;
    return (ushort)((u + 0x7fffu + ((u >> 16) & 1u)) >> 16);   // RNE
}

// ---------------- fused: out[:, :128] = x  AND  xbf = bf16(x)
__global__ __launch_bounds__(256) void convert_copy_kernel(
    const float4* __restrict__ x4, float4* __restrict__ out4,
    ushort* __restrict__ xbf, int N)
{
    int i = blockIdx.x * 256 + threadIdx.x;     // one float4 per thread
    if (i >= N * 32) return;
    float4 v = x4[i];
    int n = i >> 5, q = i & 31;
    out4[(size_t)n * 96 + q] = v;
    ushort4 b;
    b.x = f2bf(v.x); b.y = f2bf(v.y); b.z = f2bf(v.z); b.w = f2bf(v.w);
    *(ushort4*)(xbf + (size_t)i * 4) = b;
}

// ---------------- scores: su[n,o]=x·wu[o]+bu[o], sv[n,o]=x·wv[o]; 16 thr/row
__global__ __launch_bounds__(256) void scores_kernel(
    const float* __restrict__ x, const float* __restrict__ wu,
    const float* __restrict__ bu, const float* __restrict__ wv,
    float* __restrict__ su, float* __restrict__ sv, int N)
{
    __shared__ float wlds[32 * 129];
    int tid = threadIdx.x;
    for (int i = tid; i < 4096; i += 256) {
        int o = i >> 7, k = i & 127;
        wlds[o * 129 + k] = (o < 16) ? wu[i] : wv[i - 2048];
    }
    __syncthreads();
    int o = tid & 15;
    int n = blockIdx.x * 16 + (tid >> 4);
    if (n >= N) return;
    const float4* xr4 = (const float4*)(x + (size_t)n * 128);
    const float* wur = wlds + o * 129;
    const float* wvr = wlds + (16 + o) * 129;
    float au = 0.f, av = 0.f;
#pragma unroll
    for (int kk = 0; kk < 32; ++kk) {
        float4 xv = xr4[kk];
        int k = kk * 4;
        au = fmaf(xv.x, wur[k],     au);  av = fmaf(xv.x, wvr[k],     av);
        au = fmaf(xv.y, wur[k + 1], au);  av = fmaf(xv.y, wvr[k + 1], av);
        au = fmaf(xv.z, wur[k + 2], au);  av = fmaf(xv.z, wvr[k + 2], av);
        au = fmaf(xv.w, wur[k + 3], au);  av = fmaf(xv.w, wvr[k + 3], av);
    }
    su[n * 16 + o] = au + bu[o];
    sv[n * 16 + o] = av;
}

// ---------------- histogram of dst
__global__ __launch_bounds__(256) void hist_kernel(
    const int* __restrict__ d0, const int* __restrict__ d1,
    int* __restrict__ cnt, int N, int E)
{
    int idx = blockIdx.x * 256 + threadIdx.x;
    if (idx >= 2 * E) return;
    int t = (idx >= E) ? 1 : 0;
    int dst = t ? d1[idx - E] : d0[idx];
    atomicAdd(cnt + (size_t)t * N + dst, 1);
}

// ---------------- scan A: per-chunk totals
__global__ __launch_bounds__(256) void scanA_kernel(
    const int* __restrict__ cnt, int* __restrict__ partials, int N)
{
    int t = blockIdx.y, c = blockIdx.x, tid = threadIdx.x;
    const int* ct = cnt + (size_t)t * N;
    int base = c * CHUNK + tid * 8;
    int s = 0;
#pragma unroll
    for (int j = 0; j < 8; ++j) { int i = base + j; if (i < N) s += ct[i]; }
#pragma unroll
    for (int d = 1; d < 64; d <<= 1) s += __shfl_xor(s, d);
    __shared__ int wsum[4];
    if ((tid & 63) == 0) wsum[tid >> 6] = s;
    __syncthreads();
    if (tid == 0) partials[t * 32 + c] = wsum[0] + wsum[1] + wsum[2] + wsum[3];
}

// ---------------- scan B: scan the (<=32) chunk totals per edge-set
__global__ __launch_bounds__(64) void scanB_kernel(
    const int* __restrict__ partials, int* __restrict__ scanbase,
    int* __restrict__ off, int N, int nch)
{
    int lane = threadIdx.x;
    int t = lane >> 5, c = lane & 31;
    int v = (c < nch) ? partials[t * 32 + c] : 0;
    int incl = v;
#pragma unroll
    for (int d = 1; d < 32; d <<= 1) {
        int o = __shfl(incl, lane - d);
        if (c >= d) incl += o;
    }
    if (c < nch) scanbase[t * 32 + c] = incl - v;
    if (c == nch - 1) off[(size_t)t * (N + 1) + N] = incl;
}

// ---------------- scan C: final offsets + cursor init
__global__ __launch_bounds__(256) void scanC_kernel(
    const int* __restrict__ cnt, const int* __restrict__ scanbase,
    int* __restrict__ off, int* __restrict__ cursor, int N)
{
    int t = blockIdx.y, c = blockIdx.x, tid = threadIdx.x;
    const int* ct = cnt + (size_t)t * N;
    int base = c * CHUNK + tid * 8;
    int v[8], tot = 0;
#pragma unroll
    for (int j = 0; j < 8; ++j) { int i = base + j; v[j] = (i < N) ? ct[i] : 0; tot += v[j]; }
    __shared__ int lds[256];
    lds[tid] = tot;
    __syncthreads();
    int incl = tot;
    for (int d = 1; d < 256; d <<= 1) {
        int add = (tid >= d) ? lds[tid - d] : 0;
        __syncthreads();
        incl += add;
        lds[tid] = incl;
        __syncthreads();
    }
    int run = incl - tot + scanbase[t * 32 + c];
#pragma unroll
    for (int j = 0; j < 8; ++j) {
        int i = base + j;
        if (i < N) { off[(size_t)t * (N + 1) + i] = run; cursor[(size_t)t * N + i] = run; }
        run += v[j];
    }
}

// ---------------- scatter src into dst-buckets
__global__ __launch_bounds__(256) void fill_kernel(
    const int* __restrict__ s0, const int* __restrict__ d0,
    const int* __restrict__ s1, const int* __restrict__ d1,
    int* __restrict__ cursor, int* __restrict__ bucket, int N, int E)
{
    int idx = blockIdx.x * 256 + threadIdx.x;
    if (idx >= 2 * E) return;
    int t = (idx >= E) ? 1 : 0;
    int e = t ? idx - E : idx;
    int dst = t ? d1[e] : d0[e];
    int src = t ? s1[e] : s0[e];
    int pos = atomicAdd(cursor + (size_t)t * N + dst, 1);
    bucket[(size_t)t * E + pos] = src;
}

// ---------------- single-pass softmax+aggregate: one wave per (node, t)
__global__ __launch_bounds__(256) void agg_kernel(
    const ushort* __restrict__ xbf, const float* __restrict__ su,
    const float* __restrict__ sv, const int* __restrict__ off,
    const int* __restrict__ bucket, float* __restrict__ out, int N, int E)
{
    __shared__ __align__(16) float evals[4][512];
    int t = blockIdx.y;
    int wid = threadIdx.x >> 6;
    int lane = threadIdx.x & 63;
    int n = blockIdx.x * 4 + wid;
    if (n >= N) return;
    const int* offt = off + (size_t)t * (N + 1);
    const int* bkt = bucket + (size_t)t * E;
    int beg = offt[n], end = offt[n + 1];
    int h = lane & 7;            // e-phase head class
    int e8 = lane >> 3;          // e-phase edge stripe
    float vh = sv[n * 16 + t * 8 + h];
    float* ev = evals[wid];

    int hf = lane >> 5;          // acc-phase: which of 2 edges
    int q = lane & 31;
    int j0 = q * 4;              // acc-phase: 4 output elems per lane
    int hbase = (q & 1) * 4;     // heads for j0..j0+3 are hbase..hbase+3
    float acc0 = 0.f, acc1 = 0.f, acc2 = 0.f, acc3 = 0.f;
    float l = 0.f;

    for (int cbeg = beg; cbeg < end; cbeg += 64) {
        int cnt = min(end - cbeg, 64);
        int gmax = (cnt + 7) >> 3;
        // e-phase: 8 edges x 8 heads in parallel per iteration
        for (int g = 0; g < gmax; ++g) {
            int e = g * 8 + e8;
            bool valid = e < cnt;
            int srcv = 0;
            if (valid) srcv = bkt[cbeg + e];
            float s = su[srcv * 16 + t * 8 + h] + vh;
            s = (s >= 0.f) ? s : NEG_SLOPE * s;
            float eval = valid ? __expf(s) : 0.f;
            l += eval;
            ev[e * 8 + h] = eval;
        }
        // acc-phase: 2 edges per iteration (half-wave each, float4/lane)
        int pairs = (cnt + 1) >> 1;
        for (int i2 = 0; i2 < pairs; ++i2) {
            int eidx = i2 * 2 + hf;
            int srcv = 0;
            if (eidx < cnt) srcv = bkt[cbeg + eidx];
            float4 p4 = *(const float4*)(ev + eidx * 8 + hbase);
            uint2 u = *(const uint2*)(xbf + (size_t)srcv * 128 + j0);
            float x0 = __uint_as_float(u.x << 16);
            float x1 = __uint_as_float(u.x & 0xffff0000u);
            float x2 = __uint_as_float(u.y << 16);
            float x3 = __uint_as_float(u.y & 0xffff0000u);
            acc0 = fmaf(x0, p4.x, acc0);
            acc1 = fmaf(x1, p4.y, acc1);
            acc2 = fmaf(x2, p4.z, acc2);
            acc3 = fmaf(x3, p4.w, acc3);
        }
    }
    // reduce exp-sum across stripes (keeps head class h)
    l += __shfl_xor(l, 8);
    l += __shfl_xor(l, 16);
    l += __shfl_xor(l, 32);
    float invl = (l > 0.f) ? (1.f / l) : 0.f;
    // combine the two half-wave edge groups
    acc0 += __shfl_xor(acc0, 32);
    acc1 += __shfl_xor(acc1, 32);
    acc2 += __shfl_xor(acc2, 32);
    acc3 += __shfl_xor(acc3, 32);
    float i0 = __shfl(invl, hbase);
    float i1 = __shfl(invl, hbase + 1);
    float i2v = __shfl(invl, hbase + 2);
    float i3 = __shfl(invl, hbase + 3);
    if (hf == 0) {
        float4 r = make_float4(acc0 * i0, acc1 * i1, acc2 * i2v, acc3 * i3);
        *(float4*)(out + (size_t)n * 384 + 128 + (size_t)t * 128 + j0) = r;
    }
}

extern "C" void kernel_launch(void* const* d_in, const int* in_sizes, int n_in,
                              void* d_out, int out_size, void* d_ws, size_t ws_size,
                              hipStream_t stream)
{
    const float* x  = (const float*)d_in[0];
    const float* wu = (const float*)d_in[1];
    const float* bu = (const float*)d_in[2];
    const float* wv = (const float*)d_in[3];
    const int* s0 = (const int*)d_in[4];
    const int* d0 = (const int*)d_in[5];
    const int* s1 = (const int*)d_in[6];
    const int* d1 = (const int*)d_in[7];
    float* out = (float*)d_out;
    int N = in_sizes[0] / 128;
    int E = in_sizes[4];
    int nch = (N + CHUNK - 1) / CHUNK;   // 25 for N=50000 (must be <= 32)

    char* ws = (char*)d_ws;
    size_t o = 0;
    auto alloc = [&](size_t bytes) -> void* {
        void* p = ws + o;
        o = (o + bytes + 255) & ~(size_t)255;
        return p;
    };
    float* su      = (float*)alloc((size_t)N * 16 * 4);
    float* sv      = (float*)alloc((size_t)N * 16 * 4);
    int* cnt       = (int*)alloc((size_t)2 * N * 4);
    int* cursor    = (int*)alloc((size_t)2 * N * 4);
    int* off       = (int*)alloc((size_t)2 * (N + 1) * 4);
    int* partials  = (int*)alloc(64 * 4);
    int* scanbase  = (int*)alloc(64 * 4);
    int* bucket    = (int*)alloc((size_t)2 * E * 4);
    ushort* xbf    = (ushort*)alloc((size_t)N * 128 * 2);

    hipMemsetAsync(cnt, 0, (size_t)2 * N * 4, stream);
    convert_copy_kernel<<<(N * 32 + 255) / 256, 256, 0, stream>>>(
        (const float4*)x, (float4*)out, xbf, N);
    scores_kernel<<<(N + 15) / 16, 256, 0, stream>>>(x, wu, bu, wv, su, sv, N);
    hist_kernel<<<(2 * E + 255) / 256, 256, 0, stream>>>(d0, d1, cnt, N, E);
    scanA_kernel<<<dim3(nch, 2), 256, 0, stream>>>(cnt, partials, N);
    scanB_kernel<<<1, 64, 0, stream>>>(partials, scanbase, off, N, nch);
    scanC_kernel<<<dim3(nch, 2), 256, 0, stream>>>(cnt, scanbase, off, cursor, N);
    fill_kernel<<<(2 * E + 255) / 256, 256, 0, stream>>>(
        s0, d0, s1, d1, cursor, bucket, N, E);
    agg_kernel<<<dim3((N + 3) / 4, 2), 256, 0, stream>>>(
        xbf, su, sv, off, bucket, out, N, E);
}

// Round 3
// 378.361 us; speedup vs baseline: 1.4644x; 1.1506x over previous
//
#include <hip/hip_runtime.h>

#define NEG_SLOPE 0.2f
#define CHUNK 2048
#define NRANGE 8   // dst-range partitions; blockIdx.x (fastest) -> XCD round-robin

__device__ __forceinline__ ushort f2bf(float f) {
    union { float f; unsigned u; } c; c.f = f;
    unsigned u = c.u;
    return (ushort)((u + 0x7fffu + ((u >> 16) & 1u)) >> 16);   // RNE
}

// ---------------- fused: out[:, :128] = x  AND  xbf = bf16(x)
__global__ __launch_bounds__(256) void convert_copy_kernel(
    const float4* __restrict__ x4, float4* __restrict__ out4,
    ushort* __restrict__ xbf, int N)
{
    int i = blockIdx.x * 256 + threadIdx.x;     // one float4 per thread
    if (i >= N * 32) return;
    float4 v = x4[i];
    int n = i >> 5, q = i & 31;
    out4[(size_t)n * 96 + q] = v;
    ushort4 b;
    b.x = f2bf(v.x); b.y = f2bf(v.y); b.z = f2bf(v.z); b.w = f2bf(v.w);
    *(ushort4*)(xbf + (size_t)i * 4) = b;
}

// ---------------- scores: su[n,o]=x·wu[o]+bu[o], sv[n,o]=x·wv[o]; 16 thr/row
__global__ __launch_bounds__(256) void scores_kernel(
    const float* __restrict__ x, const float* __restrict__ wu,
    const float* __restrict__ bu, const float* __restrict__ wv,
    float* __restrict__ su, float* __restrict__ sv, int N)
{
    __shared__ float wlds[32 * 129];
    int tid = threadIdx.x;
    for (int i = tid; i < 4096; i += 256) {
        int o = i >> 7, k = i & 127;
        wlds[o * 129 + k] = (o < 16) ? wu[i] : wv[i - 2048];
    }
    __syncthreads();
    int o = tid & 15;
    int n = blockIdx.x * 16 + (tid >> 4);
    if (n >= N) return;
    const float4* xr4 = (const float4*)(x + (size_t)n * 128);
    const float* wur = wlds + o * 129;
    const float* wvr = wlds + (16 + o) * 129;
    float au = 0.f, av = 0.f;
#pragma unroll
    for (int kk = 0; kk < 32; ++kk) {
        float4 xv = xr4[kk];
        int k = kk * 4;
        au = fmaf(xv.x, wur[k],     au);  av = fmaf(xv.x, wvr[k],     av);
        au = fmaf(xv.y, wur[k + 1], au);  av = fmaf(xv.y, wvr[k + 1], av);
        au = fmaf(xv.z, wur[k + 2], au);  av = fmaf(xv.z, wvr[k + 2], av);
        au = fmaf(xv.w, wur[k + 3], au);  av = fmaf(xv.w, wvr[k + 3], av);
    }
    su[n * 16 + o] = au + bu[o];
    sv[n * 16 + o] = av;
}

// ---------------- histogram of dst, range-partitioned (cnt lines stay on 1 XCD)
__global__ __launch_bounds__(256) void hist_kernel(
    const int* __restrict__ d0, const int* __restrict__ d1,
    int* __restrict__ cnt, int N, int E, int rsize)
{
    int r = blockIdx.x, c = blockIdx.y, t = blockIdx.z;
    const int* dd = t ? d1 : d0;
    int lo = r * rsize, hi = min(N, lo + rsize);
    int chunk = (E + gridDim.y - 1) / gridDim.y;
    int beg = c * chunk, end = min(E, beg + chunk);
    int* ct = cnt + (size_t)t * N;
    for (int e = beg + (int)threadIdx.x; e < end; e += 256) {
        int dst = dd[e];
        if (dst >= lo && dst < hi) atomicAdd(ct + dst, 1);
    }
}

// ---------------- scan A: per-chunk totals
__global__ __launch_bounds__(256) void scanA_kernel(
    const int* __restrict__ cnt, int* __restrict__ partials, int N)
{
    int t = blockIdx.y, c = blockIdx.x, tid = threadIdx.x;
    const int* ct = cnt + (size_t)t * N;
    int base = c * CHUNK + tid * 8;
    int s = 0;
#pragma unroll
    for (int j = 0; j < 8; ++j) { int i = base + j; if (i < N) s += ct[i]; }
#pragma unroll
    for (int d = 1; d < 64; d <<= 1) s += __shfl_xor(s, d);
    __shared__ int wsum[4];
    if ((tid & 63) == 0) wsum[tid >> 6] = s;
    __syncthreads();
    if (tid == 0) partials[t * 32 + c] = wsum[0] + wsum[1] + wsum[2] + wsum[3];
}

// ---------------- scan B: scan the (<=32) chunk totals per edge-set
__global__ __launch_bounds__(64) void scanB_kernel(
    const int* __restrict__ partials, int* __restrict__ scanbase,
    int* __restrict__ off, int N, int nch)
{
    int lane = threadIdx.x;
    int t = lane >> 5, c = lane & 31;
    int v = (c < nch) ? partials[t * 32 + c] : 0;
    int incl = v;
#pragma unroll
    for (int d = 1; d < 32; d <<= 1) {
        int o = __shfl(incl, lane - d);
        if (c >= d) incl += o;
    }
    if (c < nch) scanbase[t * 32 + c] = incl - v;
    if (c == nch - 1) off[(size_t)t * (N + 1) + N] = incl;
}

// ---------------- scan C: final offsets + cursor init
__global__ __launch_bounds__(256) void scanC_kernel(
    const int* __restrict__ cnt, const int* __restrict__ scanbase,
    int* __restrict__ off, int* __restrict__ cursor, int N)
{
    int t = blockIdx.y, c = blockIdx.x, tid = threadIdx.x;
    const int* ct = cnt + (size_t)t * N;
    int base = c * CHUNK + tid * 8;
    int v[8], tot = 0;
#pragma unroll
    for (int j = 0; j < 8; ++j) { int i = base + j; v[j] = (i < N) ? ct[i] : 0; tot += v[j]; }
    __shared__ int lds[256];
    lds[tid] = tot;
    __syncthreads();
    int incl = tot;
    for (int d = 1; d < 256; d <<= 1) {
        int add = (tid >= d) ? lds[tid - d] : 0;
        __syncthreads();
        incl += add;
        lds[tid] = incl;
        __syncthreads();
    }
    int run = incl - tot + scanbase[t * 32 + c];
#pragma unroll
    for (int j = 0; j < 8; ++j) {
        int i = base + j;
        if (i < N) { off[(size_t)t * (N + 1) + i] = run; cursor[(size_t)t * N + i] = run; }
        run += v[j];
    }
}

// ---------------- scatter src into dst-buckets, range-partitioned.
// blockIdx.x = dst-range (fastest dim -> XCD via round-robin): each ~800KB
// bucket region is written by one XCD only, lines accumulate in its L2 and
// write back once (kills the 16x write amplification seen in R2).
__global__ __launch_bounds__(256) void fill_kernel(
    const int* __restrict__ s0, const int* __restrict__ d0,
    const int* __restrict__ s1, const int* __restrict__ d1,
    int* __restrict__ cursor, int* __restrict__ bucket, int N, int E, int rsize)
{
    int r = blockIdx.x, c = blockIdx.y, t = blockIdx.z;
    const int* dd = t ? d1 : d0;
    const int* ss = t ? s1 : s0;
    int lo = r * rsize, hi = min(N, lo + rsize);
    int chunk = (E + gridDim.y - 1) / gridDim.y;
    int beg = c * chunk, end = min(E, beg + chunk);
    int* cur = cursor + (size_t)t * N;
    int* bkt = bucket + (size_t)t * E;
    for (int e = beg + (int)threadIdx.x; e < end; e += 256) {
        int dst = dd[e];
        if (dst >= lo && dst < hi) {
            int pos = atomicAdd(cur + dst, 1);
            bkt[pos] = ss[e];
        }
    }
}

// ---------------- single-pass softmax+aggregate: one wave per (node, t)
__global__ __launch_bounds__(256) void agg_kernel(
    const ushort* __restrict__ xbf, const float* __restrict__ su,
    const float* __restrict__ sv, const int* __restrict__ off,
    const int* __restrict__ bucket, float* __restrict__ out, int N, int E)
{
    __shared__ __align__(16) float evals[4][512];
    int t = blockIdx.y;
    int wid = threadIdx.x >> 6;
    int lane = threadIdx.x & 63;
    int n = blockIdx.x * 4 + wid;
    if (n >= N) return;
    const int* offt = off + (size_t)t * (N + 1);
    const int* bkt = bucket + (size_t)t * E;
    int beg = offt[n], end = offt[n + 1];
    int h = lane & 7;            // e-phase head class
    int e8 = lane >> 3;          // e-phase edge stripe
    float vh = sv[n * 16 + t * 8 + h];
    float* ev = evals[wid];

    int hf = lane >> 5;          // acc-phase: which of 2 edges
    int q = lane & 31;
    int j0 = q * 4;              // acc-phase: 4 output elems per lane
    int hbase = (q & 1) * 4;     // heads for j0..j0+3 are hbase..hbase+3
    float acc0 = 0.f, acc1 = 0.f, acc2 = 0.f, acc3 = 0.f;
    float l = 0.f;

    for (int cbeg = beg; cbeg < end; cbeg += 64) {
        int cnt = min(end - cbeg, 64);
        int gmax = (cnt + 7) >> 3;
        // e-phase: 8 edges x 8 heads in parallel per iteration
        for (int g = 0; g < gmax; ++g) {
            int e = g * 8 + e8;
            bool valid = e < cnt;
            int srcv = 0;
            if (valid) srcv = bkt[cbeg + e];
            float s = su[srcv * 16 + t * 8 + h] + vh;
            s = (s >= 0.f) ? s : NEG_SLOPE * s;
            float eval = valid ? __expf(s) : 0.f;
            l += eval;
            ev[e * 8 + h] = eval;
        }
        // acc-phase: 2 edges per iteration (half-wave each, float4/lane)
        int pairs = (cnt + 1) >> 1;
        for (int i2 = 0; i2 < pairs; ++i2) {
            int eidx = i2 * 2 + hf;
            int srcv = 0;
            if (eidx < cnt) srcv = bkt[cbeg + eidx];
            float4 p4 = *(const float4*)(ev + eidx * 8 + hbase);
            uint2 u = *(const uint2*)(xbf + (size_t)srcv * 128 + j0);
            float x0 = __uint_as_float(u.x << 16);
            float x1 = __uint_as_float(u.x & 0xffff0000u);
            float x2 = __uint_as_float(u.y << 16);
            float x3 = __uint_as_float(u.y & 0xffff0000u);
            acc0 = fmaf(x0, p4.x, acc0);
            acc1 = fmaf(x1, p4.y, acc1);
            acc2 = fmaf(x2, p4.z, acc2);
            acc3 = fmaf(x3, p4.w, acc3);
        }
    }
    // reduce exp-sum across stripes (keeps head class h)
    l += __shfl_xor(l, 8);
    l += __shfl_xor(l, 16);
    l += __shfl_xor(l, 32);
    float invl = (l > 0.f) ? (1.f / l) : 0.f;
    // combine the two half-wave edge groups
    acc0 += __shfl_xor(acc0, 32);
    acc1 += __shfl_xor(acc1, 32);
    acc2 += __shfl_xor(acc2, 32);
    acc3 += __shfl_xor(acc3, 32);
    float i0 = __shfl(invl, hbase);
    float i1 = __shfl(invl, hbase + 1);
    float i2v = __shfl(invl, hbase + 2);
    float i3 = __shfl(invl, hbase + 3);
    if (hf == 0) {
        float4 r = make_float4(acc0 * i0, acc1 * i1, acc2 * i2v, acc3 * i3);
        *(float4*)(out + (size_t)n * 384 + 128 + (size_t)t * 128 + j0) = r;
    }
}

extern "C" void kernel_launch(void* const* d_in, const int* in_sizes, int n_in,
                              void* d_out, int out_size, void* d_ws, size_t ws_size,
                              hipStream_t stream)
{
    const float* x  = (const float*)d_in[0];
    const float* wu = (const float*)d_in[1];
    const float* bu = (const float*)d_in[2];
    const float* wv = (const float*)d_in[3];
    const int* s0 = (const int*)d_in[4];
    const int* d0 = (const int*)d_in[5];
    const int* s1 = (const int*)d_in[6];
    const int* d1 = (const int*)d_in[7];
    float* out = (float*)d_out;
    int N = in_sizes[0] / 128;
    int E = in_sizes[4];
    int nch = (N + CHUNK - 1) / CHUNK;        // 25 for N=50000 (<=32)
    int rsize = (N + NRANGE - 1) / NRANGE;    // 6250 dst nodes per range

    char* ws = (char*)d_ws;
    size_t o = 0;
    auto alloc = [&](size_t bytes) -> void* {
        void* p = ws + o;
        o = (o + bytes + 255) & ~(size_t)255;
        return p;
    };
    float* su      = (float*)alloc((size_t)N * 16 * 4);
    float* sv      = (float*)alloc((size_t)N * 16 * 4);
    int* cnt       = (int*)alloc((size_t)2 * N * 4);
    int* cursor    = (int*)alloc((size_t)2 * N * 4);
    int* off       = (int*)alloc((size_t)2 * (N + 1) * 4);
    int* partials  = (int*)alloc(64 * 4);
    int* scanbase  = (int*)alloc(64 * 4);
    int* bucket    = (int*)alloc((size_t)2 * E * 4);
    ushort* xbf    = (ushort*)alloc((size_t)N * 128 * 2);

    hipMemsetAsync(cnt, 0, (size_t)2 * N * 4, stream);
    convert_copy_kernel<<<(N * 32 + 255) / 256, 256, 0, stream>>>(
        (const float4*)x, (float4*)out, xbf, N);
    scores_kernel<<<(N + 15) / 16, 256, 0, stream>>>(x, wu, bu, wv, su, sv, N);
    hist_kernel<<<dim3(NRANGE, 128, 2), 256, 0, stream>>>(d0, d1, cnt, N, E, rsize);
    scanA_kernel<<<dim3(nch, 2), 256, 0, stream>>>(cnt, partials, N);
    scanB_kernel<<<1, 64, 0, stream>>>(partials, scanbase, off, N, nch);
    scanC_kernel<<<dim3(nch, 2), 256, 0, stream>>>(cnt, scanbase, off, cursor, N);
    fill_kernel<<<dim3(NRANGE, 128, 2), 256, 0, stream>>>(
        s0, d0, s1, d1, cursor, bucket, N, E, rsize);
    agg_kernel<<<dim3((N + 3) / 4, 2), 256, 0, stream>>>(
        xbf, su, sv, off, bucket, out, N, E);
}